// Round 8
// baseline (370.163 us; speedup 1.0000x reference)
//
#include <hip/hip_runtime.h>
#include <stdint.h>

// Problem geometry
#define TR  2000   // real sequence length
#define TP  2048   // padded
#define NDF 4096   // D*F
#define NB  4      // batch

typedef __attribute__((ext_vector_type(8))) short short8;
typedef __attribute__((ext_vector_type(4))) float f32x4;

static __device__ __forceinline__ unsigned short f2bf(float f) {
  union { float f; unsigned u; } v; v.f = f;
  return (unsigned short)((v.u + 0x7fffu + ((v.u >> 16) & 1u)) >> 16);
}

typedef const __attribute__((address_space(1))) void CGV;
typedef __attribute__((address_space(3))) void LV;

static __device__ __forceinline__ void async16(const void* g, void* l) {
  __builtin_amdgcn_global_load_lds((CGV*)g, (LV*)l, 16, 0, 0);
}

// ---------------------------------------------------------------------------
// Prep 1: x (B, DF, TR) fp32 -> Xb (B, DF, TP) bf16 (pad cols zero)
//                            -> Vb (B, TP, DF) bf16 (transpose; pad rows zero)
__global__ void k_prep_xv(const float* __restrict__ x,
                          unsigned short* __restrict__ Xb,
                          unsigned short* __restrict__ Vb) {
  __shared__ float tile[32][33];
  const int b  = blockIdx.z;
  const int d0 = blockIdx.x * 32;
  const int t0 = blockIdx.y * 32;
  const int lx = threadIdx.x & 31;
  const int ly = threadIdx.x >> 5;
#pragma unroll
  for (int i = 0; i < 4; ++i) {
    const int d = d0 + ly + i * 8;
    const int t = t0 + lx;
    float v = 0.f;
    if (t < TR) v = x[((size_t)b * NDF + d) * TR + t];
    tile[ly + i * 8][lx] = v;
    Xb[((size_t)b * NDF + d) * TP + t] = f2bf(v);
  }
  __syncthreads();
#pragma unroll
  for (int i = 0; i < 4; ++i) {
    const int t = t0 + ly + i * 8;
    const int d = d0 + lx;
    Vb[((size_t)b * TP + t) * NDF + d] = f2bf(tile[lx][ly + i * 8]);
  }
}

// ---------------------------------------------------------------------------
// Prep 2: Qb (B, TP, DF) bf16 = e (B, DF) + sinusoidal PE(t, df)
__global__ void k_prep_q(const float* __restrict__ e,
                         unsigned short* __restrict__ Qb) {
  const int gid = blockIdx.x * 256 + threadIdx.x;
  const int t   = gid >> 9;
  const int d0  = (gid & 511) * 8;
  float pe[8];
#pragma unroll
  for (int p = 0; p < 4; ++p) {
    const float twoi = (float)(d0 + 2 * p);
    const float dv   = expf(twoi * (-9.210340371976184f / 4096.0f));
    const float ang  = (float)t * dv;
    pe[2 * p]     = sinf(ang);
    pe[2 * p + 1] = cosf(ang);
  }
#pragma unroll
  for (int b = 0; b < NB; ++b) {
    const float* ep = e + (size_t)b * NDF + d0;
    short8 sv;
#pragma unroll
    for (int j = 0; j < 8; ++j) sv[j] = (short)f2bf(ep[j] + pe[j]);
    *(short8*)(Qb + ((size_t)b * TP + t) * NDF + d0) = sv;
  }
}

// ---------------------------------------------------------------------------
// 256x256 GEMM (B^T form): C[m][n] = sum_k A[m][k]*Bt[n][k].
// 512 thr = 8 waves (2M x 4N), per-wave 128x64, BK=64, dbuf LDS 128 KiB.
//
// REGION MAP (per buffer): A0 = A rows 0..127, A1 = rows 128..255 (wm=0
// waves read A0 only, wm=1 read A1 only; afLo = lower 64 rows of the wave's
// region, afHi = upper 64, so a region's reads drain only at Q10 (P2)).
// B0 = B rows 0..127, B1 = 128..255 (wn<2 -> B0, wn>=2 -> B1; bf01 = rows
// +0..31 of the half, bf23 = +32..63; region drains at Q01 (P1)).
//
// Schedule per K-tile kt (cur buf cb, next cbn), one-phase read-ahead:
//   P0: rd bf23(kt),afHi(kt)[cb]; stage A1(kt+1)->cbn;      MM Q00;        PB
//   P1:                                                      MM Q01; VMC0; PB
//   P2: rd afLo(kt+1)[cbn];       stage B0(kt+2)->cb;        MM Q10;       PB
//   P3: rd bf01(kt+1)[cbn];       stage A0(kt+2),B1(kt+2)->cb; MM Q11;     PB
//
// Safety (rounds 5-7 post-mortem):
//  * Write-after-read: each stage >=1 barrier after its target region's
//    drain: A1(kt+1)@P0 after prev-tile Q10@P2 (2 bars); B0(kt+2)@P2 after
//    Q01@P1 (1 bar); A0(kt+2)@P3 after Q10@P2 (1 bar); B1(kt+2)@P3 after
//    Q01@P1 (2 bars).
//  * Read-after-write: single gate vmcnt(0) at end-P1 + barrier guards ALL
//    of A0/A1/B0/B1(kt+1) for the P2/P3/next-P0 reads (vmcnt is per-wave;
//    gate-before-barrier-before-read makes it a cross-wave guarantee).
//    At the gate every outstanding load is >=1.5 phases old (~700+ cyc).
template <int LDK, bool GUARD>
__launch_bounds__(512, 2)
__global__ void k_gemm256(const unsigned short* __restrict__ A,
                          const unsigned short* __restrict__ Bt,
                          float* __restrict__ C,
                          size_t sA, size_t sB, size_t sC,
                          int ldc, int ncols) {
  __shared__ unsigned short lds[65536];   // 2 bufs x (A 16K elem | B 16K elem)
  constexpr int NT = LDK / 64;            // K-tiles, >= 4
  const int b  = blockIdx.z;
  const int m0 = blockIdx.x * 256;
  const int n0 = blockIdx.y * 256;
  const unsigned short* Ab = A + (size_t)b * sA;
  const unsigned short* Bb = Bt + (size_t)b * sB;
  const int t = threadIdx.x, w = t >> 6, l = t & 63;
  const int wm = w >> 2, wn = w & 3;
  const int lr = l & 15, lg = l >> 4;

  // staging source (inverse-swizzled global col: LDS 16B-slot s of row r
  // holds global slot s^(r&7))
  const int rofs = w * 8 + (l >> 3);
  const int csw  = ((l & 7) ^ ((l >> 3) & 7)) * 8;
  const unsigned short* gA = Ab + (size_t)(m0 + rofs) * LDK + csw;
  const unsigned short* gB = Bb + (size_t)(n0 + rofs) * LDK + csw;

#define STAGE(cb, isB, h, kt) do {                                           \
    const unsigned short* _g = ((isB) ? gB : gA)                             \
                               + (size_t)((h) * 128) * LDK + (size_t)(kt) * 64; \
    unsigned short* _d = lds + (cb) + (isB) * 16384 + (h) * 8192 + w * 512;  \
    async16(_g, _d);                                                         \
    async16(_g + (size_t)64 * LDK, _d + 4096);                               \
  } while (0)

  // swizzled k-slot offsets (elements) for ks=0,1
  const int s0 = ((0 + lg) ^ (lr & 7)) * 8;
  const int s1 = ((4 + lg) ^ (lr & 7)) * 8;
  const int aoff = wm * 8192 + lr * 64;                              // A base
  const int boff = 16384 + (wn >> 1) * 8192 + ((wn & 1) * 64 + lr) * 64; // B

#define PB do { asm volatile("" ::: "memory");                               \
                __builtin_amdgcn_s_barrier();                                \
                asm volatile("" ::: "memory"); } while (0)
#define SCHED0 __builtin_amdgcn_sched_barrier(0)
#define VMC(n) asm volatile("s_waitcnt vmcnt(" #n ")" ::: "memory")
#define RD_A(dst, base, off) do {                                            \
    _Pragma("unroll")                                                        \
    for (int f = 0; f < 4; ++f) {                                            \
      dst[f][0] = *(const short8*)((base) + ((off) + f) * 1024 + s0);        \
      dst[f][1] = *(const short8*)((base) + ((off) + f) * 1024 + s1);        \
    } } while (0)
#define RD_B(dst, base, off) do {                                            \
    _Pragma("unroll")                                                        \
    for (int f = 0; f < 2; ++f) {                                            \
      dst[f][0] = *(const short8*)((base) + ((off) + f) * 1024 + s0);        \
      dst[f][1] = *(const short8*)((base) + ((off) + f) * 1024 + s1);        \
    } } while (0)
#define MM(I0, J0, AFV, BFV) do {                                            \
    __builtin_amdgcn_s_setprio(1);                                           \
    _Pragma("unroll")                                                        \
    for (int i = 0; i < 4; ++i)                                              \
      _Pragma("unroll")                                                      \
      for (int j = 0; j < 2; ++j) {                                          \
        acc[(I0) + i][(J0) + j] = __builtin_amdgcn_mfma_f32_16x16x32_bf16(   \
            AFV[i][0], BFV[j][0], acc[(I0) + i][(J0) + j], 0, 0, 0);         \
        acc[(I0) + i][(J0) + j] = __builtin_amdgcn_mfma_f32_16x16x32_bf16(   \
            AFV[i][1], BFV[j][1], acc[(I0) + i][(J0) + j], 0, 0, 0);         \
      }                                                                      \
    __builtin_amdgcn_s_setprio(0); } while (0)

  short8 afLo[4][2], afHi[4][2], bf01[2][2], bf23[2][2];
  f32x4 acc[8][4] = {};

  // ---- prologue: buf0 = full kt0; buf1 = A0(1),B0(1),B1(1) (A1(1) comes
  //      at P0 of kt0). 14 loads; retire buf0's 8 -> vmcnt(6).
  STAGE(0, 0, 0, 0);            // A0(0)
  STAGE(0, 0, 1, 0);            // A1(0)
  STAGE(0, 1, 0, 0);            // B0(0)
  STAGE(0, 1, 1, 0);            // B1(0)
  STAGE(32768, 0, 0, 1);        // A0(1)
  STAGE(32768, 1, 0, 1);        // B0(1)
  STAGE(32768, 1, 1, 1);        // B1(1)
  VMC(6);
  PB;
  RD_B(bf01, lds + boff, 0);    // b01(0)
  RD_A(afLo, lds + aoff, 0);    // afLo(0)
  SCHED0;

  auto ktile = [&](int kt, bool nx, bool pf2) __attribute__((always_inline)) {
    const int cb  = (kt & 1) << 15;       // current buf (element offset)
    const int cbn = cb ^ 32768;           // next buf
    const unsigned short* la  = lds + cb  + aoff;
    const unsigned short* lb  = lds + cb  + boff;
    const unsigned short* laN = lds + cbn + aoff;
    const unsigned short* lbN = lds + cbn + boff;

    // P0: rd bf23(kt), afHi(kt); stage A1(kt+1)->cbn; MM Q00
    RD_B(bf23, lb, 2);
    RD_A(afHi, la, 4);
    if (nx) STAGE(cbn, 0, 1, kt + 1);
    SCHED0;
    MM(0, 0, afLo, bf01);
    PB;

    // P1: MM Q01; single gate: everything outstanding is >=1.5 phases old
    SCHED0;
    MM(0, 2, afLo, bf23);
    if (nx) VMC(0);
    PB;

    // P2: rd afLo(kt+1) [cbn A, gated]; stage B0(kt+2)->cb; MM Q10
    if (nx) RD_A(afLo, laN, 0);
    if (pf2) STAGE(cb, 1, 0, kt + 2);
    SCHED0;
    MM(4, 0, afHi, bf01);
    PB;

    // P3: rd bf01(kt+1) [cbn B, gated]; stage A0(kt+2),B1(kt+2)->cb; MM Q11
    if (nx) RD_B(bf01, lbN, 0);
    if (pf2) { STAGE(cb, 0, 0, kt + 2); STAGE(cb, 1, 1, kt + 2); }
    SCHED0;
    MM(4, 2, afHi, bf23);
    PB;
  };

  for (int kt = 0; kt < NT - 2; ++kt) ktile(kt, true, true);
  ktile(NT - 2, true, false);
  ktile(NT - 1, false, false);

#undef STAGE
#undef RD_A
#undef RD_B
#undef MM
#undef PB
#undef SCHED0
#undef VMC

  // epilogue: C/D layout col=lane&15, row=(lane>>4)*4+reg (m89-verified)
  float* Cb = C + (size_t)b * sC;
#pragma unroll
  for (int i = 0; i < 8; ++i) {
    const int rb = m0 + wm * 128 + i * 16 + lg * 4;
#pragma unroll
    for (int f = 0; f < 4; ++f) {
      const int cg = n0 + wn * 64 + f * 16 + lr;
      if (!GUARD || cg < ncols) {
#pragma unroll
        for (int j = 0; j < 4; ++j)
          Cb[(size_t)(rb + j) * ldc + cg] = acc[i][f][j];
      }
    }
  }
}

// ---------------------------------------------------------------------------
// Row softmax: P[i][j] = softmax_j(S[i][0..TR)/64), bf16 out, pad zeroed.
__global__ void k_softmax(const float* __restrict__ S,
                          unsigned short* __restrict__ P) {
  const int i = blockIdx.x;
  const int b = blockIdx.y;
  unsigned short* prow = P + ((size_t)b * TP + i) * TP;
  const int t = threadIdx.x;
  if (i >= TR) {
    for (int j = t; j < TP; j += 256) prow[j] = 0;
    return;
  }
  const float* srow = S + ((size_t)b * TP + i) * TP;
  float v[8];
  float mx = -1e30f;
#pragma unroll
  for (int r = 0; r < 8; ++r) {
    const int j = t + r * 256;
    const float s = (j < TR) ? srow[j] * 0.015625f : -1e30f;
    v[r] = s;
    mx = fmaxf(mx, s);
  }
  __shared__ float red[4];
#pragma unroll
  for (int off = 32; off > 0; off >>= 1) mx = fmaxf(mx, __shfl_xor(mx, off));
  if ((t & 63) == 0) red[t >> 6] = mx;
  __syncthreads();
  mx = fmaxf(fmaxf(red[0], red[1]), fmaxf(red[2], red[3]));
  __syncthreads();
  float sum = 0.f;
#pragma unroll
  for (int r = 0; r < 8; ++r) {
    const float ev = __expf(v[r] - mx);
    v[r] = ev;
    sum += ev;
  }
#pragma unroll
  for (int off = 32; off > 0; off >>= 1) sum += __shfl_xor(sum, off);
  if ((t & 63) == 0) red[t >> 6] = sum;
  __syncthreads();
  sum = red[0] + red[1] + red[2] + red[3];
  const float inv = 1.f / sum;
#pragma unroll
  for (int r = 0; r < 8; ++r) {
    const int j = t + r * 256;
    prow[j] = (j < TR) ? f2bf(v[r] * inv) : (unsigned short)0;
  }
}

// ---------------------------------------------------------------------------
extern "C" void kernel_launch(void* const* d_in, const int* in_sizes, int n_in,
                              void* d_out, int out_size, void* d_ws, size_t ws_size,
                              hipStream_t stream) {
  const float* x = (const float*)d_in[0];   // (B, DF, TR)
  const float* e = (const float*)d_in[1];   // (B, DF)
  float* out = (float*)d_out;               // (B, DF, TR)
  char* ws = (char*)d_ws;

  const size_t szQ = (size_t)NB * TP * NDF * 2;
  const size_t szV = szQ;
  const size_t szX = szQ;
  const size_t szS = (size_t)NB * TP * TP * 4;
  const size_t szP = (size_t)NB * TP * TP * 2;
  if (ws_size < szQ + szV + szX + szS + szP) return;

  unsigned short* Qb = (unsigned short*)(ws);
  unsigned short* Vb = (unsigned short*)(ws + szQ);
  unsigned short* Xb = (unsigned short*)(ws + szQ + szV);
  float*          S  = (float*)(ws + szQ + szV + szX);
  unsigned short* P  = (unsigned short*)(ws + szQ + szV + szX + szS);

  // 1) cast + transpose x
  k_prep_xv<<<dim3(NDF / 32, TP / 32, NB), 256, 0, stream>>>(x, Xb, Vb);
  // 2) Q = e + PE
  k_prep_q<<<dim3((TP * (NDF / 8)) / 256), 256, 0, stream>>>(e, Qb);
  // 3) S = Q * V^T   (M=TP, N=TP, K=NDF)
  k_gemm256<NDF, false><<<dim3(TP / 256, TP / 256, NB), 512, 0, stream>>>(
      Qb, Vb, S,
      (size_t)TP * NDF, (size_t)TP * NDF, (size_t)TP * TP, TP, TP);
  // 4) P = softmax(S/64)
  k_softmax<<<dim3(TP, NB), 256, 0, stream>>>(S, P);
  // 5) att^T = X * P^T  (M=NDF, N=TP, K=TP), store cols < TR
  k_gemm256<TP, true><<<dim3(NDF / 256, TP / 256, NB), 512, 0, stream>>>(
      Xb, P, out,
      (size_t)NDF * TP, (size_t)TP * TP, (size_t)NDF * TR, TR, TR);
}

// Round 9
// 359.702 us; speedup vs baseline: 1.0291x; 1.0291x over previous
//
#include <hip/hip_runtime.h>
#include <stdint.h>

// Problem geometry
#define TR  2000   // real sequence length
#define TP  2048   // padded
#define NDF 4096   // D*F
#define NB  4      // batch

typedef __attribute__((ext_vector_type(8))) short short8;
typedef __attribute__((ext_vector_type(4))) float f32x4;

static __device__ __forceinline__ unsigned short f2bf(float f) {
  union { float f; unsigned u; } v; v.f = f;
  return (unsigned short)((v.u + 0x7fffu + ((v.u >> 16) & 1u)) >> 16);
}

typedef const __attribute__((address_space(1))) void CGV;
typedef __attribute__((address_space(3))) void LV;

static __device__ __forceinline__ void async16(const void* g, void* l) {
  __builtin_amdgcn_global_load_lds((CGV*)g, (LV*)l, 16, 0, 0);
}

// ---------------------------------------------------------------------------
// Prep 1: x (B, DF, TR) fp32 -> Xb (B, DF, TP) bf16 (pad cols zero)
//                            -> Vb (B, TP, DF) bf16 (transpose; pad rows zero)
__global__ void k_prep_xv(const float* __restrict__ x,
                          unsigned short* __restrict__ Xb,
                          unsigned short* __restrict__ Vb) {
  __shared__ float tile[32][33];
  const int b  = blockIdx.z;
  const int d0 = blockIdx.x * 32;
  const int t0 = blockIdx.y * 32;
  const int lx = threadIdx.x & 31;
  const int ly = threadIdx.x >> 5;
#pragma unroll
  for (int i = 0; i < 4; ++i) {
    const int d = d0 + ly + i * 8;
    const int t = t0 + lx;
    float v = 0.f;
    if (t < TR) v = x[((size_t)b * NDF + d) * TR + t];
    tile[ly + i * 8][lx] = v;
    Xb[((size_t)b * NDF + d) * TP + t] = f2bf(v);
  }
  __syncthreads();
#pragma unroll
  for (int i = 0; i < 4; ++i) {
    const int t = t0 + ly + i * 8;
    const int d = d0 + lx;
    Vb[((size_t)b * TP + t) * NDF + d] = f2bf(tile[lx][ly + i * 8]);
  }
}

// ---------------------------------------------------------------------------
// Prep 2: Qb (B, TP, DF) bf16 = e (B, DF) + sinusoidal PE(t, df)
__global__ void k_prep_q(const float* __restrict__ e,
                         unsigned short* __restrict__ Qb) {
  const int gid = blockIdx.x * 256 + threadIdx.x;
  const int t   = gid >> 9;
  const int d0  = (gid & 511) * 8;
  float pe[8];
#pragma unroll
  for (int p = 0; p < 4; ++p) {
    const float twoi = (float)(d0 + 2 * p);
    const float dv   = expf(twoi * (-9.210340371976184f / 4096.0f));
    const float ang  = (float)t * dv;
    pe[2 * p]     = sinf(ang);
    pe[2 * p + 1] = cosf(ang);
  }
#pragma unroll
  for (int b = 0; b < NB; ++b) {
    const float* ep = e + (size_t)b * NDF + d0;
    short8 sv;
#pragma unroll
    for (int j = 0; j < 8; ++j) sv[j] = (short)f2bf(ep[j] + pe[j]);
    *(short8*)(Qb + ((size_t)b * TP + t) * NDF + d0) = sv;
  }
}

// ---------------------------------------------------------------------------
// 256x256 GEMM (B^T form): C[m][n] = sum_k A[m][k]*Bt[n][k].
// 512 thr = 8 waves (2M x 4N), per-wave 128x64, BK=64, dbuf LDS 128 KiB.
//
// FENCE DISCIPLINE (round-8 post-mortem): NO ":::memory" clobbers in the
// K-loop — memory-clobber asm makes the backend conservatively drain
// vmcnt/lgkmcnt at every phase (a per-phase __syncthreads), serializing
// reads vs MFMA (both pipes measured ~40% busy, back-to-back). Ordering is
// enforced with sched_barrier(0) (machine-level pin, no waitcnt) around raw
// s_barrier and after each clobber-free counted s_waitcnt (rule #18).
//
// Schedule per K-tile kt (cur buf cb, next cbn), one-phase read-ahead:
//   P0: rd bf23(kt),afHi(kt)[cb];                        MM Q00;          PB
//   P1:                                                   MM Q01; VMC(0); PB
//   P2: rd afLo(kt+1)[cbn]; stage B0,B1(kt+2)->cb;        MM Q10;          PB
//   P3: rd bf01(kt+1)[cbn]; stage A0,A1(kt+2)->cb;        MM Q11;          PB
//
// WAR: B0/B1(kt+2)@P2 target regions drained by Q00@P0/Q01@P1 (>=1 barrier);
// A0/A1(kt+2)@P3 drained by Q00@P0/Q10@P2 (>=1 barrier).
// RAW: single gate vmcnt(0) end-P1 retires exactly the 8 loads of kt+1
// (staged P2/P3 of kt-1, all >=2 phases old — no fresh-load stall); barrier
// after the gate makes it a cross-wave guarantee before any kt+1 read.
template <int LDK, bool GUARD>
__launch_bounds__(512, 2)
__global__ void k_gemm256(const unsigned short* __restrict__ A,
                          const unsigned short* __restrict__ Bt,
                          float* __restrict__ C,
                          size_t sA, size_t sB, size_t sC,
                          int ldc, int ncols) {
  __shared__ unsigned short lds[65536];   // 2 bufs x (A 16K elem | B 16K elem)
  constexpr int NT = LDK / 64;            // K-tiles, >= 4
  const int b  = blockIdx.z;
  const int m0 = blockIdx.x * 256;
  const int n0 = blockIdx.y * 256;
  const unsigned short* Ab = A + (size_t)b * sA;
  const unsigned short* Bb = Bt + (size_t)b * sB;
  const int t = threadIdx.x, w = t >> 6, l = t & 63;
  const int wm = w >> 2, wn = w & 3;
  const int lr = l & 15, lg = l >> 4;

  // staging source (inverse-swizzled global col: LDS 16B-slot s of row r
  // holds global slot s^(r&7))
  const int rofs = w * 8 + (l >> 3);
  const int csw  = ((l & 7) ^ ((l >> 3) & 7)) * 8;
  const unsigned short* gA = Ab + (size_t)(m0 + rofs) * LDK + csw;
  const unsigned short* gB = Bb + (size_t)(n0 + rofs) * LDK + csw;

#define STAGE(cb, isB, h, kt) do {                                           \
    const unsigned short* _g = ((isB) ? gB : gA)                             \
                               + (size_t)((h) * 128) * LDK + (size_t)(kt) * 64; \
    unsigned short* _d = lds + (cb) + (isB) * 16384 + (h) * 8192 + w * 512;  \
    async16(_g, _d);                                                         \
    async16(_g + (size_t)64 * LDK, _d + 4096);                               \
  } while (0)

  // swizzled k-slot offsets (elements) for ks=0,1
  const int s0 = ((0 + lg) ^ (lr & 7)) * 8;
  const int s1 = ((4 + lg) ^ (lr & 7)) * 8;
  const int aoff = wm * 8192 + lr * 64;                              // A base
  const int boff = 16384 + (wn >> 1) * 8192 + ((wn & 1) * 64 + lr) * 64; // B

#define SCHED0 __builtin_amdgcn_sched_barrier(0)
#define PB do { SCHED0; __builtin_amdgcn_s_barrier(); SCHED0; } while (0)
#define VMC(n) do { asm volatile("s_waitcnt vmcnt(" #n ")"); SCHED0; } while (0)
#define RD_A(dst, base, off) do {                                            \
    _Pragma("unroll")                                                        \
    for (int f = 0; f < 4; ++f) {                                            \
      dst[f][0] = *(const short8*)((base) + ((off) + f) * 1024 + s0);        \
      dst[f][1] = *(const short8*)((base) + ((off) + f) * 1024 + s1);        \
    } } while (0)
#define RD_B(dst, base, off) do {                                            \
    _Pragma("unroll")                                                        \
    for (int f = 0; f < 2; ++f) {                                            \
      dst[f][0] = *(const short8*)((base) + ((off) + f) * 1024 + s0);        \
      dst[f][1] = *(const short8*)((base) + ((off) + f) * 1024 + s1);        \
    } } while (0)
#define MM(I0, J0, AFV, BFV) do {                                            \
    __builtin_amdgcn_s_setprio(1);                                           \
    _Pragma("unroll")                                                        \
    for (int i = 0; i < 4; ++i)                                              \
      _Pragma("unroll")                                                      \
      for (int j = 0; j < 2; ++j) {                                          \
        acc[(I0) + i][(J0) + j] = __builtin_amdgcn_mfma_f32_16x16x32_bf16(   \
            AFV[i][0], BFV[j][0], acc[(I0) + i][(J0) + j], 0, 0, 0);         \
        acc[(I0) + i][(J0) + j] = __builtin_amdgcn_mfma_f32_16x16x32_bf16(   \
            AFV[i][1], BFV[j][1], acc[(I0) + i][(J0) + j], 0, 0, 0);         \
      }                                                                      \
    __builtin_amdgcn_s_setprio(0); } while (0)

  short8 afLo[4][2], afHi[4][2], bf01[2][2], bf23[2][2];
  f32x4 acc[8][4] = {};

  // ---- prologue: both K-tiles fully staged (16 loads); retire kt0's 8.
  STAGE(0, 0, 0, 0);            // A0(0)
  STAGE(0, 0, 1, 0);            // A1(0)
  STAGE(0, 1, 0, 0);            // B0(0)
  STAGE(0, 1, 1, 0);            // B1(0)
  STAGE(32768, 0, 0, 1);        // A0(1)
  STAGE(32768, 0, 1, 1);        // A1(1)
  STAGE(32768, 1, 0, 1);        // B0(1)
  STAGE(32768, 1, 1, 1);        // B1(1)
  VMC(8);
  PB;
  RD_B(bf01, lds + boff, 0);    // b01(0)
  RD_A(afLo, lds + aoff, 0);    // afLo(0)
  SCHED0;

  auto ktile = [&](int kt, bool nx, bool pf2) __attribute__((always_inline)) {
    const int cb  = (kt & 1) << 15;       // current buf (element offset)
    const int cbn = cb ^ 32768;           // next buf
    const unsigned short* la  = lds + cb  + aoff;
    const unsigned short* lb  = lds + cb  + boff;
    const unsigned short* laN = lds + cbn + aoff;
    const unsigned short* lbN = lds + cbn + boff;

    // P0: rd bf23(kt), afHi(kt); MM Q00
    RD_B(bf23, lb, 2);
    RD_A(afHi, la, 4);
    SCHED0;
    MM(0, 0, afLo, bf01);
    PB;

    // P1: MM Q01; exact gate: retires kt+1's 8 loads (all >=2 phases old)
    SCHED0;
    MM(0, 2, afLo, bf23);
    if (nx) VMC(0);
    PB;

    // P2: rd afLo(kt+1) [cbn, gated]; stage B0,B1(kt+2)->cb; MM Q10
    if (nx) RD_A(afLo, laN, 0);
    if (pf2) { STAGE(cb, 1, 0, kt + 2); STAGE(cb, 1, 1, kt + 2); }
    SCHED0;
    MM(4, 0, afHi, bf01);
    PB;

    // P3: rd bf01(kt+1) [cbn, gated]; stage A0,A1(kt+2)->cb; MM Q11
    if (nx) RD_B(bf01, lbN, 0);
    if (pf2) { STAGE(cb, 0, 0, kt + 2); STAGE(cb, 0, 1, kt + 2); }
    SCHED0;
    MM(4, 2, afHi, bf23);
    PB;
  };

  for (int kt = 0; kt < NT - 2; ++kt) ktile(kt, true, true);
  ktile(NT - 2, true, false);
  ktile(NT - 1, false, false);

#undef STAGE
#undef RD_A
#undef RD_B
#undef MM
#undef PB
#undef SCHED0
#undef VMC

  // epilogue: C/D layout col=lane&15, row=(lane>>4)*4+reg (m89-verified)
  float* Cb = C + (size_t)b * sC;
#pragma unroll
  for (int i = 0; i < 8; ++i) {
    const int rb = m0 + wm * 128 + i * 16 + lg * 4;
#pragma unroll
    for (int f = 0; f < 4; ++f) {
      const int cg = n0 + wn * 64 + f * 16 + lr;
      if (!GUARD || cg < ncols) {
#pragma unroll
        for (int j = 0; j < 4; ++j)
          Cb[(size_t)(rb + j) * ldc + cg] = acc[i][f][j];
      }
    }
  }
}

// ---------------------------------------------------------------------------
// Row softmax: P[i][j] = softmax_j(S[i][0..TR)/64), bf16 out, pad zeroed.
__global__ void k_softmax(const float* __restrict__ S,
                          unsigned short* __restrict__ P) {
  const int i = blockIdx.x;
  const int b = blockIdx.y;
  unsigned short* prow = P + ((size_t)b * TP + i) * TP;
  const int t = threadIdx.x;
  if (i >= TR) {
    for (int j = t; j < TP; j += 256) prow[j] = 0;
    return;
  }
  const float* srow = S + ((size_t)b * TP + i) * TP;
  float v[8];
  float mx = -1e30f;
#pragma unroll
  for (int r = 0; r < 8; ++r) {
    const int j = t + r * 256;
    const float s = (j < TR) ? srow[j] * 0.015625f : -1e30f;
    v[r] = s;
    mx = fmaxf(mx, s);
  }
  __shared__ float red[4];
#pragma unroll
  for (int off = 32; off > 0; off >>= 1) mx = fmaxf(mx, __shfl_xor(mx, off));
  if ((t & 63) == 0) red[t >> 6] = mx;
  __syncthreads();
  mx = fmaxf(fmaxf(red[0], red[1]), fmaxf(red[2], red[3]));
  __syncthreads();
  float sum = 0.f;
#pragma unroll
  for (int r = 0; r < 8; ++r) {
    const float ev = __expf(v[r] - mx);
    v[r] = ev;
    sum += ev;
  }
#pragma unroll
  for (int off = 32; off > 0; off >>= 1) sum += __shfl_xor(sum, off);
  if ((t & 63) == 0) red[t >> 6] = sum;
  __syncthreads();
  sum = red[0] + red[1] + red[2] + red[3];
  const float inv = 1.f / sum;
#pragma unroll
  for (int r = 0; r < 8; ++r) {
    const int j = t + r * 256;
    prow[j] = (j < TR) ? f2bf(v[r] * inv) : (unsigned short)0;
  }
}

// ---------------------------------------------------------------------------
extern "C" void kernel_launch(void* const* d_in, const int* in_sizes, int n_in,
                              void* d_out, int out_size, void* d_ws, size_t ws_size,
                              hipStream_t stream) {
  const float* x = (const float*)d_in[0];   // (B, DF, TR)
  const float* e = (const float*)d_in[1];   // (B, DF)
  float* out = (float*)d_out;               // (B, DF, TR)
  char* ws = (char*)d_ws;

  const size_t szQ = (size_t)NB * TP * NDF * 2;
  const size_t szV = szQ;
  const size_t szX = szQ;
  const size_t szS = (size_t)NB * TP * TP * 4;
  const size_t szP = (size_t)NB * TP * TP * 2;
  if (ws_size < szQ + szV + szX + szS + szP) return;

  unsigned short* Qb = (unsigned short*)(ws);
  unsigned short* Vb = (unsigned short*)(ws + szQ);
  unsigned short* Xb = (unsigned short*)(ws + szQ + szV);
  float*          S  = (float*)(ws + szQ + szV + szX);
  unsigned short* P  = (unsigned short*)(ws + szQ + szV + szX + szS);

  // 1) cast + transpose x
  k_prep_xv<<<dim3(NDF / 32, TP / 32, NB), 256, 0, stream>>>(x, Xb, Vb);
  // 2) Q = e + PE
  k_prep_q<<<dim3((TP * (NDF / 8)) / 256), 256, 0, stream>>>(e, Qb);
  // 3) S = Q * V^T   (M=TP, N=TP, K=NDF)
  k_gemm256<NDF, false><<<dim3(TP / 256, TP / 256, NB), 512, 0, stream>>>(
      Qb, Vb, S,
      (size_t)TP * NDF, (size_t)TP * NDF, (size_t)TP * TP, TP, TP);
  // 4) P = softmax(S/64)
  k_softmax<<<dim3(TP, NB), 256, 0, stream>>>(S, P);
  // 5) att^T = X * P^T  (M=NDF, N=TP, K=TP), store cols < TR
  k_gemm256<TP, true><<<dim3(NDF / 256, TP / 256, NB), 512, 0, stream>>>(
      Xb, P, out,
      (size_t)NDF * TP, (size_t)TP * TP, (size_t)NDF * TR, TR, TR);
}

// Round 10
// 353.930 us; speedup vs baseline: 1.0459x; 1.0163x over previous
//
#include <hip/hip_runtime.h>
#include <stdint.h>

// Problem geometry
#define TR  2000   // real sequence length
#define TP  2048   // padded
#define NDF 4096   // D*F
#define NB  4      // batch

typedef __attribute__((ext_vector_type(8))) short short8;
typedef __attribute__((ext_vector_type(4))) float f32x4;

static __device__ __forceinline__ unsigned short f2bf(float f) {
  union { float f; unsigned u; } v; v.f = f;
  return (unsigned short)((v.u + 0x7fffu + ((v.u >> 16) & 1u)) >> 16);
}

typedef const __attribute__((address_space(1))) void CGV;
typedef __attribute__((address_space(3))) void LV;

static __device__ __forceinline__ void async16(const void* g, void* l) {
  __builtin_amdgcn_global_load_lds((CGV*)g, (LV*)l, 16, 0, 0);
}

// ---------------------------------------------------------------------------
// Prep 1: x (B, DF, TR) fp32 -> Xb (B, DF, TP) bf16 (pad cols zero)
//                            -> Vb (B, TP, DF) bf16 (transpose; pad rows zero)
__global__ void k_prep_xv(const float* __restrict__ x,
                          unsigned short* __restrict__ Xb,
                          unsigned short* __restrict__ Vb) {
  __shared__ float tile[32][33];
  const int b  = blockIdx.z;
  const int d0 = blockIdx.x * 32;
  const int t0 = blockIdx.y * 32;
  const int lx = threadIdx.x & 31;
  const int ly = threadIdx.x >> 5;
#pragma unroll
  for (int i = 0; i < 4; ++i) {
    const int d = d0 + ly + i * 8;
    const int t = t0 + lx;
    float v = 0.f;
    if (t < TR) v = x[((size_t)b * NDF + d) * TR + t];
    tile[ly + i * 8][lx] = v;
    Xb[((size_t)b * NDF + d) * TP + t] = f2bf(v);
  }
  __syncthreads();
#pragma unroll
  for (int i = 0; i < 4; ++i) {
    const int t = t0 + ly + i * 8;
    const int d = d0 + lx;
    Vb[((size_t)b * TP + t) * NDF + d] = f2bf(tile[lx][ly + i * 8]);
  }
}

// ---------------------------------------------------------------------------
// Prep 2: Qb (B, TP, DF) bf16 = e (B, DF) + sinusoidal PE(t, df)
__global__ void k_prep_q(const float* __restrict__ e,
                         unsigned short* __restrict__ Qb) {
  const int gid = blockIdx.x * 256 + threadIdx.x;
  const int t   = gid >> 9;
  const int d0  = (gid & 511) * 8;
  float pe[8];
#pragma unroll
  for (int p = 0; p < 4; ++p) {
    const float twoi = (float)(d0 + 2 * p);
    const float dv   = expf(twoi * (-9.210340371976184f / 4096.0f));
    const float ang  = (float)t * dv;
    pe[2 * p]     = sinf(ang);
    pe[2 * p + 1] = cosf(ang);
  }
#pragma unroll
  for (int b = 0; b < NB; ++b) {
    const float* ep = e + (size_t)b * NDF + d0;
    short8 sv;
#pragma unroll
    for (int j = 0; j < 8; ++j) sv[j] = (short)f2bf(ep[j] + pe[j]);
    *(short8*)(Qb + ((size_t)b * TP + t) * NDF + d0) = sv;
  }
}

// ---------------------------------------------------------------------------
// 256x256 GEMM (B^T form): C[m][n] = sum_k A[m][k]*Bt[n][k].
// 512 thr = 8 waves (2M x 4N), per-wave 128x64, BK=64, dbuf LDS 128 KiB.
//
// FAITHFUL m201 8-phase TEMPLATE (HW-verified 1563 TF structure), mapped to
// this layout. Per phase: {ds_reads for THIS phase's MFMA; stage; barrier;
// lgkmcnt(0)+sched_barrier(0); setprio(1); 16 MFMA; setprio(0); barrier}.
// Counted vmcnt(6) ONCE per K-tile at end-Ph3 (3 half-tiles = 6 loads stay
// in flight; 4-phase landing window; never drains below 6 in steady state).
//
// Per K-tile kt (cur buf cb, next cbn):
//   Ph0: rd afLo(kt),bf01(kt) [12]; stage A1(kt+1)->cbn; lgk(8); B;lgk0; Q00; B
//   Ph1: rd bf23(kt) [4];                                 B;lgk0; Q01; B
//   Ph2: rd afHi(kt) [8]; stage B0,B1(kt+2)->cb;          B;lgk0; Q10; B
//   Ph3: stage A0(kt+2)->cb;                              B; Q11; vmc(6); B
//
// WAR (each stage >=1 barrier after its region's lgk0-drain): A1(kt+1)@Ph0
// vs A1(kt-1) reads drained Ph2(kt-1); B0/B1(kt+2)@Ph2 vs bf01(Ph0-drain)/
// bf23(Ph1-drain); A0(kt+2)@Ph3 vs afLo(Ph0)/afHi(Ph2-drain).
// RAW ledger: gate at end-Ph3(kt) retires through A1(kt+1) (8 oldest of 14),
// leaving exactly [B0B1(kt+2),A0(kt+2)]=6. Gate->barrier->read discipline.
template <int LDK, bool GUARD>
__launch_bounds__(512, 2)
__global__ void k_gemm256(const unsigned short* __restrict__ A,
                          const unsigned short* __restrict__ Bt,
                          float* __restrict__ C,
                          size_t sA, size_t sB, size_t sC,
                          int ldc, int ncols) {
  __shared__ unsigned short lds[65536];   // 2 bufs x (A 16K elem | B 16K elem)
  constexpr int NT = LDK / 64;            // K-tiles, >= 4
  const int b  = blockIdx.z;
  const int m0 = blockIdx.x * 256;
  const int n0 = blockIdx.y * 256;
  const unsigned short* Ab = A + (size_t)b * sA;
  const unsigned short* Bb = Bt + (size_t)b * sB;
  const int t = threadIdx.x, w = t >> 6, l = t & 63;
  const int wm = w >> 2, wn = w & 3;
  const int lr = l & 15, lg = l >> 4;

  // staging source (inverse-swizzled global col: LDS 16B-slot s of row r
  // holds global slot s^(r&7))
  const int rofs = w * 8 + (l >> 3);
  const int csw  = ((l & 7) ^ ((l >> 3) & 7)) * 8;
  const unsigned short* gA = Ab + (size_t)(m0 + rofs) * LDK + csw;
  const unsigned short* gB = Bb + (size_t)(n0 + rofs) * LDK + csw;

#define STAGE(cb, isB, h, kt) do {                                           \
    const unsigned short* _g = ((isB) ? gB : gA)                             \
                               + (size_t)((h) * 128) * LDK + (size_t)(kt) * 64; \
    unsigned short* _d = lds + (cb) + (isB) * 16384 + (h) * 8192 + w * 512;  \
    async16(_g, _d);                                                         \
    async16(_g + (size_t)64 * LDK, _d + 4096);                               \
  } while (0)

  // swizzled k-slot offsets (elements) for ks=0,1
  const int s0 = ((0 + lg) ^ (lr & 7)) * 8;
  const int s1 = ((4 + lg) ^ (lr & 7)) * 8;
  const int aoff = wm * 8192 + lr * 64;                              // A base
  const int boff = 16384 + (wn >> 1) * 8192 + ((wn & 1) * 64 + lr) * 64; // B

#define SCHED0 __builtin_amdgcn_sched_barrier(0)
#define PB do { SCHED0; __builtin_amdgcn_s_barrier(); SCHED0; } while (0)
#define VMC(n) do { asm volatile("s_waitcnt vmcnt(" #n ")"); SCHED0; } while (0)
#define LGK(n) do { asm volatile("s_waitcnt lgkmcnt(" #n ")"); SCHED0; } while (0)
#define RD_A(dst, base, off) do {                                            \
    _Pragma("unroll")                                                        \
    for (int f = 0; f < 4; ++f) {                                            \
      dst[f][0] = *(const short8*)((base) + ((off) + f) * 1024 + s0);        \
      dst[f][1] = *(const short8*)((base) + ((off) + f) * 1024 + s1);        \
    } } while (0)
#define RD_B(dst, base, off) do {                                            \
    _Pragma("unroll")                                                        \
    for (int f = 0; f < 2; ++f) {                                            \
      dst[f][0] = *(const short8*)((base) + ((off) + f) * 1024 + s0);        \
      dst[f][1] = *(const short8*)((base) + ((off) + f) * 1024 + s1);        \
    } } while (0)
#define MM(I0, J0, AFV, BFV) do {                                            \
    __builtin_amdgcn_s_setprio(1);                                           \
    _Pragma("unroll")                                                        \
    for (int i = 0; i < 4; ++i)                                              \
      _Pragma("unroll")                                                      \
      for (int j = 0; j < 2; ++j) {                                          \
        acc[(I0) + i][(J0) + j] = __builtin_amdgcn_mfma_f32_16x16x32_bf16(   \
            AFV[i][0], BFV[j][0], acc[(I0) + i][(J0) + j], 0, 0, 0);         \
        acc[(I0) + i][(J0) + j] = __builtin_amdgcn_mfma_f32_16x16x32_bf16(   \
            AFV[i][1], BFV[j][1], acc[(I0) + i][(J0) + j], 0, 0, 0);         \
      }                                                                      \
    __builtin_amdgcn_s_setprio(0); } while (0)

  short8 afLo[4][2], afHi[4][2], bf01[2][2], bf23[2][2];
  f32x4 acc[8][4] = {};

  // ---- prologue: kt0 fully + A0,B0,B1(1) (14 loads); retire kt0's 8.
  STAGE(0, 0, 0, 0);            // A0(0)
  STAGE(0, 0, 1, 0);            // A1(0)
  STAGE(0, 1, 0, 0);            // B0(0)
  STAGE(0, 1, 1, 0);            // B1(0)
  STAGE(32768, 0, 0, 1);        // A0(1)
  STAGE(32768, 1, 0, 1);        // B0(1)
  STAGE(32768, 1, 1, 1);        // B1(1)
  VMC(6);
  PB;

  auto ktile = [&](int kt, bool nx, bool pf2) __attribute__((always_inline)) {
    const int cb  = (kt & 1) << 15;       // current buf (element offset)
    const int cbn = cb ^ 32768;           // next buf
    const unsigned short* la = lds + cb + aoff;
    const unsigned short* lb = lds + cb + boff;

    // Ph0: rd afLo(kt), bf01(kt); stage A1(kt+1)->cbn
    RD_A(afLo, la, 0);
    RD_B(bf01, lb, 0);
    if (nx) STAGE(cbn, 0, 1, kt + 1);
    LGK(8);                      // throttle (12-read phase, per template)
    PB;
    LGK(0);
    MM(0, 0, afLo, bf01);
    PB;

    // Ph1: rd bf23(kt)
    RD_B(bf23, lb, 2);
    PB;
    LGK(0);
    MM(0, 2, afLo, bf23);
    PB;

    // Ph2: rd afHi(kt); stage B0,B1(kt+2)->cb
    RD_A(afHi, la, 4);
    if (pf2) { STAGE(cb, 1, 0, kt + 2); STAGE(cb, 1, 1, kt + 2); }
    PB;
    LGK(0);
    MM(4, 0, afHi, bf01);
    PB;

    // Ph3: stage A0(kt+2)->cb; Q11; counted gate (once per K-tile)
    if (pf2) STAGE(cb, 0, 0, kt + 2);
    PB;
    MM(4, 2, afHi, bf23);
    if (nx) { if (pf2) VMC(6); else VMC(0); }
    PB;
  };

  for (int kt = 0; kt < NT - 2; ++kt) ktile(kt, true, true);
  ktile(NT - 2, true, false);
  ktile(NT - 1, false, false);

#undef STAGE
#undef RD_A
#undef RD_B
#undef MM
#undef PB
#undef SCHED0
#undef VMC
#undef LGK

  // epilogue: C/D layout col=lane&15, row=(lane>>4)*4+reg (m89-verified)
  float* Cb = C + (size_t)b * sC;
#pragma unroll
  for (int i = 0; i < 8; ++i) {
    const int rb = m0 + wm * 128 + i * 16 + lg * 4;
#pragma unroll
    for (int f = 0; f < 4; ++f) {
      const int cg = n0 + wn * 64 + f * 16 + lr;
      if (!GUARD || cg < ncols) {
#pragma unroll
        for (int j = 0; j < 4; ++j)
          Cb[(size_t)(rb + j) * ldc + cg] = acc[i][f][j];
      }
    }
  }
}

// ---------------------------------------------------------------------------
// Row softmax: P[i][j] = softmax_j(S[i][0..TR)/64), bf16 out, pad zeroed.
__global__ void k_softmax(const float* __restrict__ S,
                          unsigned short* __restrict__ P) {
  const int i = blockIdx.x;
  const int b = blockIdx.y;
  unsigned short* prow = P + ((size_t)b * TP + i) * TP;
  const int t = threadIdx.x;
  if (i >= TR) {
    for (int j = t; j < TP; j += 256) prow[j] = 0;
    return;
  }
  const float* srow = S + ((size_t)b * TP + i) * TP;
  float v[8];
  float mx = -1e30f;
#pragma unroll
  for (int r = 0; r < 8; ++r) {
    const int j = t + r * 256;
    const float s = (j < TR) ? srow[j] * 0.015625f : -1e30f;
    v[r] = s;
    mx = fmaxf(mx, s);
  }
  __shared__ float red[4];
#pragma unroll
  for (int off = 32; off > 0; off >>= 1) mx = fmaxf(mx, __shfl_xor(mx, off));
  if ((t & 63) == 0) red[t >> 6] = mx;
  __syncthreads();
  mx = fmaxf(fmaxf(red[0], red[1]), fmaxf(red[2], red[3]));
  __syncthreads();
  float sum = 0.f;
#pragma unroll
  for (int r = 0; r < 8; ++r) {
    const float ev = __expf(v[r] - mx);
    v[r] = ev;
    sum += ev;
  }
#pragma unroll
  for (int off = 32; off > 0; off >>= 1) sum += __shfl_xor(sum, off);
  if ((t & 63) == 0) red[t >> 6] = sum;
  __syncthreads();
  sum = red[0] + red[1] + red[2] + red[3];
  const float inv = 1.f / sum;
#pragma unroll
  for (int r = 0; r < 8; ++r) {
    const int j = t + r * 256;
    prow[j] = (j < TR) ? f2bf(v[r] * inv) : (unsigned short)0;
  }
}

// ---------------------------------------------------------------------------
extern "C" void kernel_launch(void* const* d_in, const int* in_sizes, int n_in,
                              void* d_out, int out_size, void* d_ws, size_t ws_size,
                              hipStream_t stream) {
  const float* x = (const float*)d_in[0];   // (B, DF, TR)
  const float* e = (const float*)d_in[1];   // (B, DF)
  float* out = (float*)d_out;               // (B, DF, TR)
  char* ws = (char*)d_ws;

  const size_t szQ = (size_t)NB * TP * NDF * 2;
  const size_t szV = szQ;
  const size_t szX = szQ;
  const size_t szS = (size_t)NB * TP * TP * 4;
  const size_t szP = (size_t)NB * TP * TP * 2;
  if (ws_size < szQ + szV + szX + szS + szP) return;

  unsigned short* Qb = (unsigned short*)(ws);
  unsigned short* Vb = (unsigned short*)(ws + szQ);
  unsigned short* Xb = (unsigned short*)(ws + szQ + szV);
  float*          S  = (float*)(ws + szQ + szV + szX);
  unsigned short* P  = (unsigned short*)(ws + szQ + szV + szX + szS);

  // 1) cast + transpose x
  k_prep_xv<<<dim3(NDF / 32, TP / 32, NB), 256, 0, stream>>>(x, Xb, Vb);
  // 2) Q = e + PE
  k_prep_q<<<dim3((TP * (NDF / 8)) / 256), 256, 0, stream>>>(e, Qb);
  // 3) S = Q * V^T   (M=TP, N=TP, K=NDF)
  k_gemm256<NDF, false><<<dim3(TP / 256, TP / 256, NB), 512, 0, stream>>>(
      Qb, Vb, S,
      (size_t)TP * NDF, (size_t)TP * NDF, (size_t)TP * TP, TP, TP);
  // 4) P = softmax(S/64)
  k_softmax<<<dim3(TP, NB), 256, 0, stream>>>(S, P);
  // 5) att^T = X * P^T  (M=NDF, N=TP, K=TP), store cols < TR
  k_gemm256<TP, true><<<dim3(NDF / 256, TP / 256, NB), 512, 0, stream>>>(
      Xb, P, out,
      (size_t)NDF * TP, (size_t)TP * TP, (size_t)NDF * TR, TR, TR);
}